// Round 4
// baseline (690.520 us; speedup 1.0000x reference)
//
#include <hip/hip_runtime.h>
#include <math.h>

#define DIM      128
#define HEADS    8
#define NCLS     64
#define NEG_SLOPE 0.2f
#define SCAN_THREADS 1024
#define NPB      64    // nodes per block (classifier GEMM tile)
#define NPB32    32    // nodes per block (gather-GEMM tiles)
#define APAD     132   // LDS row stride (floats): 16B-aligned rows, bank offset 4/row

// ----------------------------------------------------------- degree histogram
__global__ void deg_hist(const int* __restrict__ dst, int* __restrict__ deg, int E) {
    int e = blockIdx.x * blockDim.x + threadIdx.x;
    if (e < E) atomicAdd(&deg[dst[e]], 1);
}

// ------------------- single-block exclusive scan over N degrees -> rowstart
__global__ void scan_kernel(const int* __restrict__ deg, int* __restrict__ rowstart, int N) {
    __shared__ int sums[SCAN_THREADS];
    int t = threadIdx.x;
    int chunk = (N + SCAN_THREADS - 1) / SCAN_THREADS;
    int beg = t * chunk;
    int end = min(beg + chunk, N);
    int s = 0;
    for (int i = beg; i < end; ++i) s += deg[i];
    sums[t] = s;
    __syncthreads();
    for (int off = 1; off < SCAN_THREADS; off <<= 1) {
        int v = (t >= off) ? sums[t - off] : 0;
        __syncthreads();
        sums[t] += v;
        __syncthreads();
    }
    int run = (t == 0) ? 0 : sums[t - 1];
    for (int i = beg; i < end; ++i) { rowstart[i] = run; run += deg[i]; }
    if (t == SCAN_THREADS - 1) rowstart[N] = sums[SCAN_THREADS - 1];
}

// ------------------------- bucket fill: 1 atomic per edge; stores src AND dst
__global__ void fill_csr(const int* __restrict__ src, const int* __restrict__ dst,
                         const int* __restrict__ rowstart, int* __restrict__ cursor,
                         int* __restrict__ csr_src, int* __restrict__ csr_dst, int E) {
    int e = blockIdx.x * blockDim.x + threadIdx.x;
    if (e >= E) return;
    int d = dst[e];
    int pos = rowstart[d] + atomicAdd(&cursor[d], 1);
    csr_src[pos] = src[e];
    csr_dst[pos] = d;
}

// ===== GCN layer: 32-node tile. Phase 1: float4-lane gather (wave = 2 nodes in
//       parallel, x4 edge unroll -> 4x16B in flight/lane). Phase 2: register GEMM
//       (2 nodes x 8 feats / thread), W read once per block.
__global__ __launch_bounds__(256, 8)
void gcn_fused3(const float* __restrict__ x, const int* __restrict__ rowstart,
                const int* __restrict__ csr_src, const float* __restrict__ W,
                const float* __restrict__ b, float* __restrict__ out, int N) {
    __shared__ float A[NPB32 * APAD];                // 16896 B -> 8 blocks/CU
    int n0 = blockIdx.x * NPB32;
    int tid = threadIdx.x;
    int wave = tid >> 6, lane = tid & 63;
    int half = lane >> 5;                            // which node of the pair
    int q = lane & 31;                               // float4 group within row
    const float4* xf = (const float4*)x;

    for (int pair = 0; pair < 4; ++pair) {
        int nl = wave * 8 + pair * 2 + half;
        int n = n0 + nl;
        float4 acc = make_float4(0.f, 0.f, 0.f, 0.f);
        if (n < N) {
            int beg = rowstart[n], end = rowstart[n + 1];
            int it = beg;
            for (; it + 4 <= end; it += 4) {
                int s0 = csr_src[it], s1 = csr_src[it + 1];
                int s2 = csr_src[it + 2], s3 = csr_src[it + 3];
                float4 v0 = xf[(size_t)s0 * 32 + q];
                float4 v1 = xf[(size_t)s1 * 32 + q];
                float4 v2 = xf[(size_t)s2 * 32 + q];
                float4 v3 = xf[(size_t)s3 * 32 + q];
                acc.x += (v0.x + v1.x) + (v2.x + v3.x);
                acc.y += (v0.y + v1.y) + (v2.y + v3.y);
                acc.z += (v0.z + v1.z) + (v2.z + v3.z);
                acc.w += (v0.w + v1.w) + (v2.w + v3.w);
            }
            for (; it < end; ++it) {
                float4 v = xf[(size_t)csr_src[it] * 32 + q];
                acc.x += v.x; acc.y += v.y; acc.z += v.z; acc.w += v.w;
            }
            float inv = 1.f / fmaxf((float)(end - beg), 1.f);
            acc.x *= inv; acc.y *= inv; acc.z *= inv; acc.w *= inv;
        }
        *(float4*)&A[nl * APAD + 4 * q] = acc;
    }
    __syncthreads();

    // Phase 2: thread -> feats [f0,f0+8), nodes [nm,nm+2)
    int fg = tid & 15, ng = tid >> 4;
    int f0 = fg * 8, nm = ng * 2;
    float acc2[2][8];
#pragma unroll
    for (int r = 0; r < 2; ++r)
#pragma unroll
        for (int c = 0; c < 8; ++c) acc2[r][c] = 0.f;

    const float4* W4 = (const float4*)W;
#pragma unroll 4
    for (int k = 0; k < DIM; ++k) {
        float a0 = A[nm * APAD + k];
        float a1 = A[(nm + 1) * APAD + k];
        float wv[8];
        *(float4*)&wv[0] = W4[k * 32 + fg * 2];
        *(float4*)&wv[4] = W4[k * 32 + fg * 2 + 1];
#pragma unroll
        for (int c = 0; c < 8; ++c) {
            acc2[0][c] = fmaf(a0, wv[c], acc2[0][c]);
            acc2[1][c] = fmaf(a1, wv[c], acc2[1][c]);
        }
    }
    float bias[8];
    *(float4*)&bias[0] = ((const float4*)b)[fg * 2];
    *(float4*)&bias[4] = ((const float4*)b)[fg * 2 + 1];
#pragma unroll
    for (int r = 0; r < 2; ++r) {
        int n = n0 + nm + r;
        if (n < N) {
            float4 o0, o1;
            o0.x = fmaxf(acc2[r][0] + bias[0], 0.f); o0.y = fmaxf(acc2[r][1] + bias[1], 0.f);
            o0.z = fmaxf(acc2[r][2] + bias[2], 0.f); o0.w = fmaxf(acc2[r][3] + bias[3], 0.f);
            o1.x = fmaxf(acc2[r][4] + bias[4], 0.f); o1.y = fmaxf(acc2[r][5] + bias[5], 0.f);
            o1.z = fmaxf(acc2[r][6] + bias[6], 0.f); o1.w = fmaxf(acc2[r][7] + bias[7], 0.f);
            float4* op = (float4*)(out + (size_t)n * DIM + f0);
            op[0] = o0; op[1] = o1;
        }
    }
}

// ===== GAT h: 32-node tile GEMM h = x @ Wg, with e_s/e_d dot epilogue
__global__ __launch_bounds__(256, 8)
void gat_h3(const float* __restrict__ x, const float* __restrict__ Wg,
            const float* __restrict__ a_src, const float* __restrict__ a_dst,
            float* __restrict__ h, float* __restrict__ e_s, float* __restrict__ e_d, int N) {
    __shared__ float A[NPB32 * APAD];
    int n0 = blockIdx.x * NPB32;
    int tid = threadIdx.x;
    for (int idx = tid; idx < NPB32 * 32; idx += 256) {
        int nl = idx >> 5, q = idx & 31;
        int n = n0 + nl;
        float4 v = (n < N) ? ((const float4*)x)[(size_t)n * 32 + q]
                           : make_float4(0.f, 0.f, 0.f, 0.f);
        *(float4*)&A[nl * APAD + q * 4] = v;
    }
    __syncthreads();

    int fg = tid & 15, ng = tid >> 4;
    int f0 = fg * 8, nm = ng * 2;
    float acc[2][8];
#pragma unroll
    for (int r = 0; r < 2; ++r)
#pragma unroll
        for (int c = 0; c < 8; ++c) acc[r][c] = 0.f;

    const float4* W4 = (const float4*)Wg;
#pragma unroll 4
    for (int k = 0; k < DIM; ++k) {
        float a0 = A[nm * APAD + k];
        float a1 = A[(nm + 1) * APAD + k];
        float wv[8];
        *(float4*)&wv[0] = W4[k * 32 + fg * 2];
        *(float4*)&wv[4] = W4[k * 32 + fg * 2 + 1];
#pragma unroll
        for (int c = 0; c < 8; ++c) {
            acc[0][c] = fmaf(a0, wv[c], acc[0][c]);
            acc[1][c] = fmaf(a1, wv[c], acc[1][c]);
        }
    }
    int head = fg >> 1, sub = (fg & 1) * 8;
    float as[8], ad[8];
#pragma unroll
    for (int j = 0; j < 8; ++j) {
        as[j] = a_src[head * 16 + sub + j];
        ad[j] = a_dst[head * 16 + sub + j];
    }
#pragma unroll
    for (int r = 0; r < 2; ++r) {
        int n = n0 + nm + r;
        float ps = 0.f, pd = 0.f;
#pragma unroll
        for (int c = 0; c < 8; ++c) {
            ps = fmaf(acc[r][c], as[c], ps);
            pd = fmaf(acc[r][c], ad[c], pd);
        }
        ps += __shfl_xor(ps, 1);
        pd += __shfl_xor(pd, 1);
        if (n < N) {
            float4 o0 = {acc[r][0], acc[r][1], acc[r][2], acc[r][3]};
            float4 o1 = {acc[r][4], acc[r][5], acc[r][6], acc[r][7]};
            float4* hp = (float4*)(h + (size_t)n * DIM + f0);
            hp[0] = o0; hp[1] = o1;
            if (!(fg & 1)) {
                e_s[n * HEADS + head] = ps;
                e_d[n * HEADS + head] = pd;
            }
        }
    }
}

// -------- scores in CSR order: sexp[pos*8+h] = exp(leaky_relu(e_s[src]+e_d[dst]))
__global__ void gat_score_csr(const int* __restrict__ csr_src, const int* __restrict__ csr_dst,
                              const float* __restrict__ e_s, const float* __restrict__ e_d,
                              float* __restrict__ sexp, int E) {
    int tid = blockIdx.x * blockDim.x + threadIdx.x;
    if (tid >= E * HEADS) return;
    int p = tid >> 3;
    int hh = tid & (HEADS - 1);
    float sc = e_s[csr_src[p] * HEADS + hh] + e_d[csr_dst[p] * HEADS + hh];
    sc = (sc > 0.0f) ? sc : NEG_SLOPE * sc;
    sexp[tid] = expf(sc);           // max-shift skipped: |sc| small, fp32-safe
}

// ===== GAT aggregate + link head: wave = 2 nodes, float4 lanes, sexp sequential
__global__ __launch_bounds__(256, 8)
void gat_fused3(const float* __restrict__ h, const int* __restrict__ rowstart,
                const int* __restrict__ csr_src, const float* __restrict__ sexp,
                const float* __restrict__ bg, const float* __restrict__ Wl,
                const float* __restrict__ bl, float* __restrict__ out_link, int N) {
    int tid = threadIdx.x;
    int wave = tid >> 6, lane = tid & 63;
    int half = lane >> 5, q = lane & 31;
    int n = blockIdx.x * 8 + wave * 2 + half;
    if (n >= N) return;
    int head = q >> 2;              // feats 4q..4q+3 all in head q/4
    const float4* hf = (const float4*)h;
    int beg = rowstart[n], end = rowstart[n + 1];
    float4 acc = make_float4(0.f, 0.f, 0.f, 0.f);
    float den = 0.f;
    int it = beg;
    for (; it + 4 <= end; it += 4) {
        int s0 = csr_src[it], s1 = csr_src[it + 1], s2 = csr_src[it + 2], s3 = csr_src[it + 3];
        float ex0 = sexp[(size_t)it * HEADS + head];
        float ex1 = sexp[(size_t)(it + 1) * HEADS + head];
        float ex2 = sexp[(size_t)(it + 2) * HEADS + head];
        float ex3 = sexp[(size_t)(it + 3) * HEADS + head];
        float4 v0 = hf[(size_t)s0 * 32 + q];
        float4 v1 = hf[(size_t)s1 * 32 + q];
        float4 v2 = hf[(size_t)s2 * 32 + q];
        float4 v3 = hf[(size_t)s3 * 32 + q];
        den += (ex0 + ex1) + (ex2 + ex3);
        acc.x = fmaf(v0.x, ex0, acc.x); acc.y = fmaf(v0.y, ex0, acc.y);
        acc.z = fmaf(v0.z, ex0, acc.z); acc.w = fmaf(v0.w, ex0, acc.w);
        acc.x = fmaf(v1.x, ex1, acc.x); acc.y = fmaf(v1.y, ex1, acc.y);
        acc.z = fmaf(v1.z, ex1, acc.z); acc.w = fmaf(v1.w, ex1, acc.w);
        acc.x = fmaf(v2.x, ex2, acc.x); acc.y = fmaf(v2.y, ex2, acc.y);
        acc.z = fmaf(v2.z, ex2, acc.z); acc.w = fmaf(v2.w, ex2, acc.w);
        acc.x = fmaf(v3.x, ex3, acc.x); acc.y = fmaf(v3.y, ex3, acc.y);
        acc.z = fmaf(v3.z, ex3, acc.z); acc.w = fmaf(v3.w, ex3, acc.w);
    }
    for (; it < end; ++it) {
        int s = csr_src[it];
        float ex = sexp[(size_t)it * HEADS + head];
        float4 v = hf[(size_t)s * 32 + q];
        den += ex;
        acc.x = fmaf(v.x, ex, acc.x); acc.y = fmaf(v.y, ex, acc.y);
        acc.z = fmaf(v.z, ex, acc.z); acc.w = fmaf(v.w, ex, acc.w);
    }
    float inv = 1.f / (den + 1e-9f);
    float4 bgv = ((const float4*)bg)[q];
    float4 wl4 = ((const float4*)Wl)[q];
    float x0 = fmaxf(acc.x * inv + bgv.x, 0.f);
    float x1 = fmaxf(acc.y * inv + bgv.y, 0.f);
    float x2 = fmaxf(acc.z * inv + bgv.z, 0.f);
    float x3 = fmaxf(acc.w * inv + bgv.w, 0.f);
    float p = fmaf(x0, wl4.x, fmaf(x1, wl4.y, fmaf(x2, wl4.z, x3 * wl4.w)));
    for (int off = 16; off; off >>= 1) p += __shfl_xor(p, off);   // within 32-lane half
    if (q == 0) out_link[n] = 1.f / (1.f + expf(-(p + bl[0])));
}

// ===== classifier: 64-node x 64-class tiled GEMM + in-register softmax
__global__ __launch_bounds__(256, 4)
void classifier2(const float* __restrict__ x2, const float* __restrict__ Wcls,
                 const float* __restrict__ bcls, float* __restrict__ out, int N) {
    __shared__ float A[NPB * APAD];
    int n0 = blockIdx.x * NPB;
    int tid = threadIdx.x;
    for (int idx = tid; idx < NPB * 32; idx += 256) {
        int nl = idx >> 5, q = idx & 31;
        int n = n0 + nl;
        float4 v = (n < N) ? ((const float4*)x2)[(size_t)n * 32 + q]
                           : make_float4(0.f, 0.f, 0.f, 0.f);
        *(float4*)&A[nl * APAD + q * 4] = v;
    }
    __syncthreads();

    int cg = tid & 15, ng = tid >> 4;     // 4 classes, 4 nodes per thread
    int c0 = cg * 4, nm = ng * 4;
    float acc[4][4];
#pragma unroll
    for (int r = 0; r < 4; ++r)
#pragma unroll
        for (int c = 0; c < 4; ++c) acc[r][c] = 0.f;

    const float4* W4 = (const float4*)Wcls;   // [128][16 float4]
#pragma unroll 4
    for (int k = 0; k < DIM; ++k) {
        float av[4];
#pragma unroll
        for (int r = 0; r < 4; ++r) av[r] = A[(nm + r) * APAD + k];
        float wv[4];
        *(float4*)&wv[0] = W4[k * 16 + cg];
#pragma unroll
        for (int r = 0; r < 4; ++r)
#pragma unroll
            for (int c = 0; c < 4; ++c) acc[r][c] = fmaf(av[r], wv[c], acc[r][c]);
    }
    float4 bv = ((const float4*)bcls)[cg];
    float bias[4] = {bv.x, bv.y, bv.z, bv.w};
#pragma unroll
    for (int r = 0; r < 4; ++r) {
        int n = n0 + nm + r;
        float l[4];
        float m = -1e30f;
#pragma unroll
        for (int c = 0; c < 4; ++c) { l[c] = acc[r][c] + bias[c]; m = fmaxf(m, l[c]); }
        for (int off = 1; off < 16; off <<= 1) m = fmaxf(m, __shfl_xor(m, off));
        float s = 0.f;
#pragma unroll
        for (int c = 0; c < 4; ++c) { l[c] = expf(l[c] - m); s += l[c]; }
        for (int off = 1; off < 16; off <<= 1) s += __shfl_xor(s, off);
        float invs = 1.f / s;
        if (n < N) {
            float4 o = {l[0] * invs, l[1] * invs, l[2] * invs, l[3] * invs};
            *(float4*)(out + (size_t)n * NCLS + c0) = o;
        }
    }
}

extern "C" void kernel_launch(void* const* d_in, const int* in_sizes, int n_in,
                              void* d_out, int out_size, void* d_ws, size_t ws_size,
                              hipStream_t stream) {
    const float* xin   = (const float*)d_in[0];
    const int*   eidx  = (const int*)  d_in[1];
    const float* W1    = (const float*)d_in[2];
    const float* b1    = (const float*)d_in[3];
    const float* W2    = (const float*)d_in[4];
    const float* b2    = (const float*)d_in[5];
    const float* Wg    = (const float*)d_in[6];
    const float* bg    = (const float*)d_in[7];
    const float* a_src = (const float*)d_in[8];
    const float* a_dst = (const float*)d_in[9];
    const float* Wcls  = (const float*)d_in[10];
    const float* bcls  = (const float*)d_in[11];
    const float* Wl    = (const float*)d_in[12];
    const float* bl    = (const float*)d_in[13];

    const int N = in_sizes[0] / DIM;
    const int E = in_sizes[1] / 2;
    const int* src = eidx;
    const int* dst = eidx + E;

    // workspace layout (4B elems):
    int*   deg      = (int*)d_ws;
    int*   rowstart = deg + N;
    int*   cursor   = rowstart + (N + 1);
    int*   csr_src  = cursor + N;
    int*   csr_dst  = csr_src + E;
    float* bufA     = (float*)(csr_dst + E);           // x1, later h
    float* bufB     = bufA + (size_t)N * DIM;          // x2
    float* e_s      = bufB + (size_t)N * DIM;
    float* e_d      = e_s + (size_t)N * HEADS;
    float* sexp     = e_d + (size_t)N * HEADS;         // E*HEADS, CSR order

    float* out_cls  = (float*)d_out;                   // [N, 64]
    float* out_link = out_cls + (size_t)N * NCLS;      // [N, 1]

    int blkE   = (E + 255) / 256;
    int blkEH  = (E * HEADS + 255) / 256;
    int blkN32 = (N + NPB32 - 1) / NPB32;
    int blkN64 = (N + NPB - 1) / NPB;

    // ---- CSR build (once; shared by all three aggregation passes)
    hipMemsetAsync(deg, 0, (size_t)N * sizeof(int), stream);
    deg_hist<<<blkE, 256, 0, stream>>>(dst, deg, E);
    scan_kernel<<<1, SCAN_THREADS, 0, stream>>>(deg, rowstart, N);
    hipMemsetAsync(cursor, 0, (size_t)N * sizeof(int), stream);
    fill_csr<<<blkE, 256, 0, stream>>>(src, dst, rowstart, cursor, csr_src, csr_dst, E);

    // ---- GCN layers (gather + tiled GEMM, no atomics)
    gcn_fused3<<<blkN32, 256, 0, stream>>>(xin,  rowstart, csr_src, W1, b1, bufA, N);
    gcn_fused3<<<blkN32, 256, 0, stream>>>(bufA, rowstart, csr_src, W2, b2, bufB, N);

    // ---- classifier head
    classifier2<<<blkN64, 256, 0, stream>>>(bufB, Wcls, bcls, out_cls, N);

    // ---- GAT branch (bufA reusable after GCN2 consumed it)
    gat_h3<<<blkN32, 256, 0, stream>>>(xin, Wg, a_src, a_dst, bufA, e_s, e_d, N);
    gat_score_csr<<<blkEH, 256, 0, stream>>>(csr_src, csr_dst, e_s, e_d, sexp, E);
    gat_fused3<<<(N + 7) / 8, 256, 0, stream>>>(bufA, rowstart, csr_src, sexp,
                                                bg, Wl, bl, out_link, N);
}